// Round 9
// baseline (205.553 us; speedup 1.0000x reference)
//
#include <hip/hip_runtime.h>

#define BB 8
#define CC 128

// ---------------- fused inLay: global->combine->LDS(stride 68) + sample + box mask ----
__global__ __launch_bounds__(256) void inlay_sample_kernel(
    const float* __restrict__ x, const float* __restrict__ lin,
    const float* __restrict__ geo, const float* __restrict__ box,
    float* __restrict__ out) {
  const int H = 64, W = 64, HW = 4096;
  __shared__ __align__(16) float cp[64 * 68];   // 17.4 KB combined plane
  int bc = blockIdx.x;
  int c = bc & (CC - 1);
  int b = bc >> 7;
  int tid = threadIdx.x;
  const float* xb = x + (size_t)b * 3 * HW;

  float w0 = lin[c * 3 + 0], w1 = lin[c * 3 + 1], w2 = lin[c * 3 + 2];

#pragma unroll
  for (int k = 0; k < 4; ++k) {
    int i4 = tid + k * 256;
    int base = i4 * 4;
    float4 f0 = *reinterpret_cast<const float4*>(&xb[base]);
    float4 f1 = *reinterpret_cast<const float4*>(&xb[HW + base]);
    float4 f2 = *reinterpret_cast<const float4*>(&xb[2 * HW + base]);
    float4 cv;
    cv.x = w0 * f0.x + w1 * f1.x + w2 * f2.x;
    cv.y = w0 * f0.y + w1 * f1.y + w2 * f2.y;
    cv.z = w0 * f0.z + w1 * f1.z + w2 * f2.z;
    cv.w = w0 * f0.w + w1 * f1.w + w2 * f2.w;
    int h = i4 >> 4, w = (i4 & 15) * 4;
    *reinterpret_cast<float4*>(&cp[h * 68 + w]) = cv;
  }
  __syncthreads();

  const float* g = geo + c * 6;
  const float* bx = box + c * 6;
  float g0 = g[0], g1 = g[1], g2 = g[2], g3 = g[3], g4 = g[4], g5 = g[5];
  float b0 = bx[0], b1 = bx[1], b2 = bx[2], b3 = bx[3], b4 = bx[4], b5 = bx[5];
  float* o = out + ((size_t)b * CC + c) * HW;

#pragma unroll
  for (int k = 0; k < 16; ++k) {
    int px = tid + k * 256;
    int h = px >> 6, w = px & 63;
    float xs = (2.0f * w + 1.0f) / W - 1.0f;
    float ys = (2.0f * h + 1.0f) / H - 1.0f;
    float gx = g0 * xs + g1 * ys + g2;
    float gy = g3 * xs + g4 * ys + g5;
    float ix = ((gx + 1.0f) * W - 1.0f) * 0.5f;
    float iy = ((gy + 1.0f) * H - 1.0f) * 0.5f;
    float x0 = floorf(ix), y0 = floorf(iy);
    float wx = ix - x0, wy = iy - y0;
    float v[2][2];
#pragma unroll
    for (int dy = 0; dy < 2; ++dy)
#pragma unroll
      for (int dx = 0; dx < 2; ++dx) {
        float xf = x0 + dx, yf = y0 + dy;
        bool valid = (xf >= 0.0f) && (xf <= 63.0f) && (yf >= 0.0f) && (yf <= 63.0f);
        int xi = (int)fminf(fmaxf(xf, 0.0f), 63.0f);
        int yi = (int)fminf(fmaxf(yf, 0.0f), 63.0f);
        v[dy][dx] = valid ? cp[yi * 68 + xi] : 0.0f;
      }
    float samp = (1.0f - wy) * ((1.0f - wx) * v[0][0] + wx * v[0][1]) +
                 wy * ((1.0f - wx) * v[1][0] + wx * v[1][1]);

    float bgx = b0 * xs + b1 * ys + b2;
    float bgy = b3 * xs + b4 * ys + b5;
    float bix = ((bgx + 1.0f) * W - 1.0f) * 0.5f;
    float biy = ((bgy + 1.0f) * H - 1.0f) * 0.5f;
    float bx0 = floorf(bix), by0 = floorf(biy);
    float bwx = bix - bx0, bwy = biy - by0;
    float m[2][2];
#pragma unroll
    for (int dy = 0; dy < 2; ++dy)
#pragma unroll
      for (int dx = 0; dx < 2; ++dx) {
        float xf = bx0 + dx, yf = by0 + dy;
        m[dy][dx] = ((xf >= 0.0f) && (xf <= 63.0f) && (yf >= 0.0f) && (yf <= 63.0f)) ? 1.0f : 0.0f;
      }
    float mask = (1.0f - bwy) * ((1.0f - bwx) * m[0][0] + bwx * m[0][1]) +
                 bwy * ((1.0f - bwx) * m[1][0] + bwx * m[1][1]);
    o[px] = samp * mask;
  }
}

// ---------------- fused layer0+1: GEMM (1 ch/block, k-ascending) + sample + maxpool --
// Grid 1024 x 1024 threads. LDS 43 KB -> 2 blocks/CU co-resident (vs round-7's 1).
// GEMM per-element FMA chain identical to gemm64's (k ascending) -> bit-identical.
// XCD swizzle: b = blockIdx & 7 pins each batch's 2 MB input to one XCD L2.
__global__ __launch_bounds__(1024, 4) void fused_gsamp_kernel(
    const float* __restrict__ lin, const float* __restrict__ x,
    const float* __restrict__ geo, const float* __restrict__ box,
    float* __restrict__ out) {
  __shared__ __align__(16) float sp[64 * 68];      // sampled plane, padded stride
  __shared__ __align__(16) float arena[64 * 100];  // pl (GEMM out) then cb
  __shared__ float wv[16];
  __shared__ int wi[16];
  __shared__ int am_s;
  float* pl = arena;
  float* cb = arena;

  int b = blockIdx.x & 7;
  int c = blockIdx.x >> 3;
  int tid = threadIdx.x;
  const float* xb = x + (size_t)b * 128 * 4096;
  const float* lc = lin + c * 128;
  int px4 = tid * 4;

  // ---- GEMM: one output channel, k ascending (bit-identical chain) ----
  float4 acc = make_float4(0.f, 0.f, 0.f, 0.f);
#pragma unroll 8
  for (int k = 0; k < 128; ++k) {
    float4 xv = *reinterpret_cast<const float4*>(&xb[(size_t)k * 4096 + px4]);
    float s = lc[k];                       // block-uniform -> s_load
    acc.x += s * xv.x; acc.y += s * xv.y; acc.z += s * xv.z; acc.w += s * xv.w;
  }
  *reinterpret_cast<float4*>(&pl[px4]) = acc;   // contiguous 64-wide layout
  __syncthreads();

  // ---- phase 2: sample 4 px/thread -> sp (round-8-validated) ----
  {
    const float* g = geo + c * 6;
    const float* bx = box + c * 6;
    float g0 = g[0], g1 = g[1], g2 = g[2], g3 = g[3], g4 = g[4], g5 = g[5];
    float b0 = bx[0], b1 = bx[1], b2 = bx[2], b3 = bx[3], b4 = bx[4], b5 = bx[5];
#pragma unroll
    for (int k = 0; k < 4; ++k) {
      int px = tid + k * 1024;
      int h = px >> 6, w = px & 63;
      float xs = (2.0f * w + 1.0f) / 64.0f - 1.0f;
      float ys = (2.0f * h + 1.0f) / 64.0f - 1.0f;
      float gx = g0 * xs + g1 * ys + g2;
      float gy = g3 * xs + g4 * ys + g5;
      float ix = ((gx + 1.0f) * 64.0f - 1.0f) * 0.5f;
      float iy = ((gy + 1.0f) * 64.0f - 1.0f) * 0.5f;
      float x0 = floorf(ix), y0 = floorf(iy);
      float wx = ix - x0, wy = iy - y0;
      float v[2][2];
#pragma unroll
      for (int dy = 0; dy < 2; ++dy)
#pragma unroll
        for (int dx = 0; dx < 2; ++dx) {
          float xf = x0 + dx, yf = y0 + dy;
          bool valid = (xf >= 0.0f) && (xf <= 63.0f) && (yf >= 0.0f) && (yf <= 63.0f);
          int xi = (int)fminf(fmaxf(xf, 0.0f), 63.0f);
          int yi = (int)fminf(fmaxf(yf, 0.0f), 63.0f);
          v[dy][dx] = valid ? pl[yi * 64 + xi] : 0.0f;
        }
      float samp = (1.0f - wy) * ((1.0f - wx) * v[0][0] + wx * v[0][1]) +
                   wy * ((1.0f - wx) * v[1][0] + wx * v[1][1]);
      float bgx = b0 * xs + b1 * ys + b2;
      float bgy = b3 * xs + b4 * ys + b5;
      float bix = ((bgx + 1.0f) * 64.0f - 1.0f) * 0.5f;
      float biy = ((bgy + 1.0f) * 64.0f - 1.0f) * 0.5f;
      float bx0 = floorf(bix), by0 = floorf(biy);
      float bwx = bix - bx0, bwy = biy - by0;
      float m[2][2];
#pragma unroll
      for (int dy = 0; dy < 2; ++dy)
#pragma unroll
        for (int dx = 0; dx < 2; ++dx) {
          float xf = bx0 + dx, yf = by0 + dy;
          m[dy][dx] = ((xf >= 0.0f) && (xf <= 63.0f) && (yf >= 0.0f) && (yf <= 63.0f)) ? 1.0f : 0.0f;
        }
      float mask = (1.0f - bwy) * ((1.0f - bwx) * m[0][0] + bwx * m[0][1]) +
                   bwy * ((1.0f - bwx) * m[1][0] + bwx * m[1][1]);
      sp[h * 68 + w] = samp * mask;
    }
  }
  __syncthreads();   // pl dead; cb (same arena) written next

  // ---- phase 3: column band sums (strips of 4 rows; pads zeroed) ----
  if (tid < 256) {
    int strip = tid >> 4, w4 = (tid & 15) * 4;
    int h0 = strip * 4;
    float4 a0 = make_float4(0.f, 0.f, 0.f, 0.f), a1 = a0, a2 = a0, a3 = a0;
#pragma unroll
    for (int j = 0; j < 35; ++j) {
      int r = h0 + j - 16;
      bool valid = (r >= 0) && (r < 64);
      int rc = valid ? r : 0;
      float4 f = *reinterpret_cast<const float4*>(&sp[rc * 68 + w4]);
      f.x = valid ? f.x : 0.0f; f.y = valid ? f.y : 0.0f;
      f.z = valid ? f.z : 0.0f; f.w = valid ? f.w : 0.0f;
      if (j <= 31) { a0.x += f.x; a0.y += f.y; a0.z += f.z; a0.w += f.w; }
      if (j >= 1 && j <= 32) { a1.x += f.x; a1.y += f.y; a1.z += f.z; a1.w += f.w; }
      if (j >= 2 && j <= 33) { a2.x += f.x; a2.y += f.y; a2.z += f.z; a2.w += f.w; }
      if (j >= 3) { a3.x += f.x; a3.y += f.y; a3.z += f.z; a3.w += f.w; }
    }
    *reinterpret_cast<float4*>(&cb[(h0 + 0) * 100 + 16 + w4]) = a0;
    *reinterpret_cast<float4*>(&cb[(h0 + 1) * 100 + 16 + w4]) = a1;
    *reinterpret_cast<float4*>(&cb[(h0 + 2) * 100 + 16 + w4]) = a2;
    *reinterpret_cast<float4*>(&cb[(h0 + 3) * 100 + 16 + w4]) = a3;
  } else if (tid < 768) {
    int l = tid - 256;
    int row = l >> 3, gq = l & 7;
    int base = row * 100 + ((gq < 4) ? gq * 4 : 80 + (gq - 4) * 4);
    *reinterpret_cast<float4*>(&cb[base]) = make_float4(0.f, 0.f, 0.f, 0.f);
  }
  __syncthreads();

  // ---- phase 4: row window sums + argmax ----
  float best = -3.402823466e+38f;
  int bidx = 0x7fffffff;
  {
    int h = tid >> 4, w4 = (tid & 15) * 4;
    float s0 = 0.f, s1 = 0.f, s2 = 0.f, s3 = 0.f;
#pragma unroll
    for (int q = 0; q < 9; ++q) {
      float4 f = *reinterpret_cast<const float4*>(&cb[h * 100 + w4 + 4 * q]);
      float fe[4] = {f.x, f.y, f.z, f.w};
#pragma unroll
      for (int e = 0; e < 4; ++e) {
        int u = 4 * q + e;
        if (u <= 31) s0 += fe[e];
        if (u >= 1 && u <= 32) s1 += fe[e];
        if (u >= 2 && u <= 33) s2 += fe[e];
        if (u >= 3 && u <= 34) s3 += fe[e];
      }
    }
    float sv[4] = {s0, s1, s2, s3};
#pragma unroll
    for (int d = 0; d < 4; ++d) {
      int i = (h << 6) + w4 + d;
      if (sv[d] > best) { best = sv[d]; bidx = i; }
    }
  }
#pragma unroll
  for (int off = 32; off > 0; off >>= 1) {
    float v2 = __shfl_down(best, off);
    int i2 = __shfl_down(bidx, off);
    if (v2 > best || (v2 == best && i2 < bidx)) { best = v2; bidx = i2; }
  }
  if ((tid & 63) == 0) { wv[tid >> 6] = best; wi[tid >> 6] = bidx; }
  __syncthreads();
  if (tid == 0) {
    float bv = wv[0]; int bi = wi[0];
#pragma unroll
    for (int k = 1; k < 16; ++k)
      if (wv[k] > bv || (wv[k] == bv && wi[k] < bi)) { bv = wv[k]; bi = wi[k]; }
    am_s = bi;
  }
  __syncthreads();

  // ---- phase 5: 32x32 windowed gather ----
  int am = am_s;
  int r = am >> 6, cx = am & 63;
  float* o = out + ((size_t)b * CC + c) * 1024;
  {
    int oi = tid >> 5, oj = tid & 31;
    int rr = r + oi - 16, cj = cx + oj - 16;
    bool v = (rr >= 0) && (rr < 64) && (cj >= 0) && (cj < 64);
    int rrc = v ? rr : 0, cjc = v ? cj : 0;
    o[tid] = v ? sp[rrc * 68 + cjc] : 0.0f;
  }
}

// ---------------- fused 32x32 layer: GEMM (2 ch/block, grid 512) + sample + pool ----
template <bool POOL>
__global__ __launch_bounds__(256) void fused32_kernel(
    const float* __restrict__ lin, const float* __restrict__ x,
    const float* __restrict__ geo, const float* __restrict__ box,
    float* __restrict__ out, float* __restrict__ pooled) {
  const int H = 32, W = 32, HW = 1024;
  __shared__ __align__(16) float pls[2][1024];
  __shared__ float wred[8];
  int b = blockIdx.x & 7;                 // XCD swizzle: batch per XCD
  int c0 = (blockIdx.x >> 3) * 2;
  int tid = threadIdx.x;
  const float* xb = x + (size_t)b * 128 * HW;
  const float* l0 = lin + (c0 + 0) * 128;
  const float* l1 = lin + (c0 + 1) * 128;
  int px4 = tid * 4;

  float4 acc0 = make_float4(0.f, 0.f, 0.f, 0.f);
  float4 acc1 = acc0;
#pragma unroll 8
  for (int k = 0; k < 128; ++k) {
    float4 xv = *reinterpret_cast<const float4*>(&xb[(size_t)k * HW + px4]);
    float s0 = l0[k], s1 = l1[k];          // block-uniform -> s_load
    acc0.x += s0 * xv.x; acc0.y += s0 * xv.y; acc0.z += s0 * xv.z; acc0.w += s0 * xv.w;
    acc1.x += s1 * xv.x; acc1.y += s1 * xv.y; acc1.z += s1 * xv.z; acc1.w += s1 * xv.w;
  }
  *reinterpret_cast<float4*>(&pls[0][px4]) = acc0;
  *reinterpret_cast<float4*>(&pls[1][px4]) = acc1;
  __syncthreads();

  float psum[2] = {0.f, 0.f};
#pragma unroll
  for (int c = 0; c < 2; ++c) {
    const float* g = geo + (c0 + c) * 6;
    const float* bxp = box + (c0 + c) * 6;
    float g0 = g[0], g1 = g[1], g2 = g[2], g3 = g[3], g4 = g[4], g5 = g[5];
    float b0 = bxp[0], b1 = bxp[1], b2 = bxp[2], b3 = bxp[3], b4 = bxp[4], b5 = bxp[5];
    float* o = out + ((size_t)b * CC + c0 + c) * HW;
    const float* pl = pls[c];
#pragma unroll
    for (int k = 0; k < 4; ++k) {
      int px = tid + k * 256;
      int h = px >> 5, w = px & 31;
      float xs = (2.0f * w + 1.0f) / W - 1.0f;
      float ys = (2.0f * h + 1.0f) / H - 1.0f;
      float gx = g0 * xs + g1 * ys + g2;
      float gy = g3 * xs + g4 * ys + g5;
      float ix = ((gx + 1.0f) * W - 1.0f) * 0.5f;
      float iy = ((gy + 1.0f) * H - 1.0f) * 0.5f;
      float x0 = floorf(ix), y0 = floorf(iy);
      float wx = ix - x0, wy = iy - y0;
      float v[2][2];
#pragma unroll
      for (int dy = 0; dy < 2; ++dy)
#pragma unroll
        for (int dx = 0; dx < 2; ++dx) {
          float xf = x0 + dx, yf = y0 + dy;
          bool valid = (xf >= 0.0f) && (xf <= 31.0f) && (yf >= 0.0f) && (yf <= 31.0f);
          int xi = (int)fminf(fmaxf(xf, 0.0f), 31.0f);
          int yi = (int)fminf(fmaxf(yf, 0.0f), 31.0f);
          v[dy][dx] = valid ? pl[yi * 32 + xi] : 0.0f;
        }
      float samp = (1.0f - wy) * ((1.0f - wx) * v[0][0] + wx * v[0][1]) +
                   wy * ((1.0f - wx) * v[1][0] + wx * v[1][1]);
      float bgx = b0 * xs + b1 * ys + b2;
      float bgy = b3 * xs + b4 * ys + b5;
      float bix = ((bgx + 1.0f) * W - 1.0f) * 0.5f;
      float biy = ((bgy + 1.0f) * H - 1.0f) * 0.5f;
      float bx0 = floorf(bix), by0 = floorf(biy);
      float bwx = bix - bx0, bwy = biy - by0;
      float m[2][2];
#pragma unroll
      for (int dy = 0; dy < 2; ++dy)
#pragma unroll
        for (int dx = 0; dx < 2; ++dx) {
          float xf = bx0 + dx, yf = by0 + dy;
          m[dy][dx] = ((xf >= 0.0f) && (xf <= 31.0f) && (yf >= 0.0f) && (yf <= 31.0f)) ? 1.0f : 0.0f;
        }
      float mask = (1.0f - bwy) * ((1.0f - bwx) * m[0][0] + bwx * m[0][1]) +
                   bwy * ((1.0f - bwx) * m[1][0] + bwx * m[1][1]);
      float res = samp * mask;
      o[px] = res;
      if (POOL) psum[c] += res;
    }
  }
  if (POOL) {
    int lane = tid & 63, wid = tid >> 6;
#pragma unroll
    for (int c = 0; c < 2; ++c) {
      float r = psum[c];
#pragma unroll
      for (int off = 32; off > 0; off >>= 1) r += __shfl_down(r, off);
      if (lane == 0) wred[c * 4 + wid] = r;
    }
    __syncthreads();
    if (tid < 2) {
      float t = wred[tid * 4] + wred[tid * 4 + 1] + wred[tid * 4 + 2] + wred[tid * 4 + 3];
      pooled[b * CC + c0 + tid] = t * (1.0f / 1024.0f);
    }
  }
}

// ---------------- dense head ----------------
__global__ __launch_bounds__(128) void dense_kernel(
    const float* __restrict__ pooled, const float* __restrict__ w,
    const float* __restrict__ bias, float* __restrict__ out) {
  int t = threadIdx.x;
  if (t < 80) {
    int b = t / 10, o = t % 10;
    float s = bias[o];
    const float* pb = pooled + b * 128;
    const float* wo = w + o * 128;
    for (int c = 0; c < 128; ++c) s += pb[c] * wo[c];
    out[b * 10 + o] = s;
  }
}

extern "C" void kernel_launch(void* const* d_in, const int* in_sizes, int n_in,
                              void* d_out, int out_size, void* d_ws, size_t ws_size,
                              hipStream_t stream) {
  const float* x     = (const float*)d_in[0];   // [8,3,64,64]
  const float* geo0  = (const float*)d_in[1];   // [128,2,3]
  const float* lin0  = (const float*)d_in[2];   // [128,3]
  const float* box0  = (const float*)d_in[3];   // [128,2,3]
  const float* geos  = (const float*)d_in[4];   // [3,128,2,3]
  const float* lins  = (const float*)d_in[5];   // [3,128,128]
  const float* boxes = (const float*)d_in[6];   // [3,128,2,3]
  const float* dw    = (const float*)d_in[7];   // [10,128]
  const float* db    = (const float*)d_in[8];   // [10]

  float* out  = (float*)d_out;      // [8,10] then feat [8,128,32,32]
  float* feat = out + 80;
  float* ws   = (float*)d_ws;
  float* ws0  = ws;                 // 16 MB
  float* ws1  = ws + 4194304;       // 16 MB
  float* pooled = ws + 8388608;     // 1024 floats

  // inLay: fused combine(Ci=3) + sample -> ws1
  inlay_sample_kernel<<<dim3(BB * CC), 256, 0, stream>>>(x, lin0, geo0, box0, ws1);
  // layer 0+1: fused GEMM(1ch/block) + sample + maxpool -> [8,128,32,32] in ws0
  fused_gsamp_kernel<<<dim3(1024), 1024, 0, stream>>>(lins, ws1, geos, boxes, ws0);
  // layer 2: fused GEMM + sample (2 ch/block, grid 512)
  fused32_kernel<false><<<dim3(512), 256, 0, stream>>>(lins + 16384, ws0, geos + 768, boxes + 768, ws1, nullptr);
  // layer 3: fused GEMM + sample + mean-pool, feat straight to d_out
  fused32_kernel<true><<<dim3(512), 256, 0, stream>>>(lins + 32768, ws1, geos + 1536, boxes + 1536, feat, pooled);
  // head
  dense_kernel<<<1, 128, 0, stream>>>(pooled, dw, db, out);
}

// Round 10
// 184.398 us; speedup vs baseline: 1.1147x; 1.1147x over previous
//
#include <hip/hip_runtime.h>

#define BB 8
#define CC 128

// ---------- fused inLay+layer0 GEMM: sample B on the fly, 128x64 tile ----------
// grid (64 col-tiles, 8 batches), 256 threads. Each B element used by exactly one
// block -> sampling here duplicates no work vs a standalone inlay kernel.
// Sample expression identical to prior inlay; MAC chain k-ascending == gemm64.
__global__ __launch_bounds__(256) void inlay_gemm_kernel(
    const float* __restrict__ x, const float* __restrict__ lin0,
    const float* __restrict__ geo0, const float* __restrict__ box0,
    const float* __restrict__ lins, float* __restrict__ y) {
  __shared__ __align__(16) float xpl[3][64 * 68];   // 52.2 KB input planes
  __shared__ __align__(16) float As[16][132];       // 8.4 KB
  __shared__ __align__(16) float Bs[16][64];        // 4 KB
  int colt = blockIdx.x;            // column tile = output row h (64 px = one row)
  int b = blockIdx.y;
  int tid = threadIdx.x;
  int col0 = colt * 64;
  const float* xb = x + (size_t)b * 3 * 4096;
  float* yb = y + (size_t)b * CC * 4096;

  // stage 3 input planes at stride 68
#pragma unroll
  for (int q = 0; q < 12; ++q) {
    int i4 = tid + q * 256;         // 0..3071 float4 groups (3 planes x 1024)
    int p = i4 >> 10;               // plane
    int r = (i4 & 1023);            // float4 within plane
    int h = r >> 4, w = (r & 15) * 4;
    *reinterpret_cast<float4*>(&xpl[p][h * 68 + w]) =
        *reinterpret_cast<const float4*>(&xb[p * 4096 + r * 4]);
  }
  __syncthreads();

  int ty = tid >> 4, tx = tid & 15;
  int am = tid >> 2, akq = (tid & 3) * 4;
  float acc[8][4] = {};

  const int hrow = colt;            // global row of all 64 pixels in this tile
  const float ys = (2.0f * hrow + 1.0f) / 64.0f - 1.0f;

  for (int k0 = 0; k0 < 128; k0 += 16) {
    __syncthreads();                // previous MAC done before overwrite
    // stage A chunk (transposed, float4 along k)
#pragma unroll
    for (int q = 0; q < 2; ++q) {
      int l = tid + q * 256;
      int m = l >> 2;
      float4 av = *reinterpret_cast<const float4*>(&lins[m * 128 + k0 + akq]);
      (void)av;
      // recompute with per-l kq (akq is tid-based; must use l-based)
      int kq = (l & 3) * 4;
      float4 av2 = *reinterpret_cast<const float4*>(&lins[m * 128 + k0 + kq]);
      As[kq + 0][m] = av2.x; As[kq + 1][m] = av2.y;
      As[kq + 2][m] = av2.z; As[kq + 3][m] = av2.w;
    }
    // stage B chunk: sample 16 channels x 64 px (4 samples/thread)
#pragma unroll
    for (int q = 0; q < 4; ++q) {
      int l = tid + q * 256;
      int kk = l >> 6;              // 0..15
      int w = l & 63;
      int ch = k0 + kk;
      float w0 = lin0[ch * 3 + 0], w1 = lin0[ch * 3 + 1], w2 = lin0[ch * 3 + 2];
      const float* g = geo0 + ch * 6;
      const float* bx = box0 + ch * 6;
      float xs = (2.0f * w + 1.0f) / 64.0f - 1.0f;
      float gx = g[0] * xs + g[1] * ys + g[2];
      float gy = g[3] * xs + g[4] * ys + g[5];
      float ix = ((gx + 1.0f) * 64.0f - 1.0f) * 0.5f;
      float iy = ((gy + 1.0f) * 64.0f - 1.0f) * 0.5f;
      float x0 = floorf(ix), y0 = floorf(iy);
      float wx = ix - x0, wy = iy - y0;
      float v[2][2];
#pragma unroll
      for (int dy = 0; dy < 2; ++dy)
#pragma unroll
        for (int dx = 0; dx < 2; ++dx) {
          float xf = x0 + dx, yf = y0 + dy;
          bool valid = (xf >= 0.0f) && (xf <= 63.0f) && (yf >= 0.0f) && (yf <= 63.0f);
          int xi = (int)fminf(fmaxf(xf, 0.0f), 63.0f);
          int yi = (int)fminf(fmaxf(yf, 0.0f), 63.0f);
          int t = yi * 68 + xi;
          float vv = w0 * xpl[0][t] + w1 * xpl[1][t] + w2 * xpl[2][t];
          v[dy][dx] = valid ? vv : 0.0f;
        }
      float samp = (1.0f - wy) * ((1.0f - wx) * v[0][0] + wx * v[0][1]) +
                   wy * ((1.0f - wx) * v[1][0] + wx * v[1][1]);
      float bgx = bx[0] * xs + bx[1] * ys + bx[2];
      float bgy = bx[3] * xs + bx[4] * ys + bx[5];
      float bix = ((bgx + 1.0f) * 64.0f - 1.0f) * 0.5f;
      float biy = ((bgy + 1.0f) * 64.0f - 1.0f) * 0.5f;
      float bx0 = floorf(bix), by0 = floorf(biy);
      float bwx = bix - bx0, bwy = biy - by0;
      float m[2][2];
#pragma unroll
      for (int dy = 0; dy < 2; ++dy)
#pragma unroll
        for (int dx = 0; dx < 2; ++dx) {
          float xf = bx0 + dx, yf = by0 + dy;
          m[dy][dx] = ((xf >= 0.0f) && (xf <= 63.0f) && (yf >= 0.0f) && (yf <= 63.0f)) ? 1.0f : 0.0f;
        }
      float mask = (1.0f - bwy) * ((1.0f - bwx) * m[0][0] + bwx * m[0][1]) +
                   bwy * ((1.0f - bwx) * m[1][0] + bwx * m[1][1]);
      Bs[kk][w] = samp * mask;
    }
    __syncthreads();
    // MAC: 8 rows x 4 cols per thread, k ascending (bit-identical chain)
#pragma unroll
    for (int kki = 0; kki < 16; ++kki) {
      float a[8], bv[4];
      *reinterpret_cast<float4*>(&a[0]) = *reinterpret_cast<const float4*>(&As[kki][ty * 8]);
      *reinterpret_cast<float4*>(&a[4]) = *reinterpret_cast<const float4*>(&As[kki][ty * 8 + 4]);
      *reinterpret_cast<float4*>(&bv[0]) = *reinterpret_cast<const float4*>(&Bs[kki][tx * 4]);
#pragma unroll
      for (int i = 0; i < 8; i++)
#pragma unroll
        for (int j = 0; j < 4; j++) acc[i][j] += a[i] * bv[j];
    }
  }
#pragma unroll
  for (int i = 0; i < 8; i++) {
    float* yr = yb + (size_t)(ty * 8 + i) * 4096 + col0 + tx * 4;
    *reinterpret_cast<float4*>(yr) = make_float4(acc[i][0], acc[i][1], acc[i][2], acc[i][3]);
  }
}

// ---------------- fused sample(64x64) + MaxPool2d_G -> 32x32, 1024 threads ---------
__global__ __launch_bounds__(1024, 4) void sampmax_kernel(
    const float* __restrict__ y, const float* __restrict__ geo,
    const float* __restrict__ box, float* __restrict__ out) {
  __shared__ __align__(16) float sp[64 * 68];
  __shared__ __align__(16) float arena[64 * 100];
  __shared__ float wv[16];
  __shared__ int wi[16];
  __shared__ int am_s;
  float* pl = arena;
  float* cb = arena;

  int bc = blockIdx.x;
  int c = bc & (CC - 1);
  int b = bc >> 7;
  int tid = threadIdx.x;

  const float* plane = y + (size_t)bc * 4096;
  *reinterpret_cast<float4*>(&pl[tid * 4]) = *reinterpret_cast<const float4*>(&plane[tid * 4]);
  __syncthreads();

  {
    const float* g = geo + c * 6;
    const float* bx = box + c * 6;
    float g0 = g[0], g1 = g[1], g2 = g[2], g3 = g[3], g4 = g[4], g5 = g[5];
    float b0 = bx[0], b1 = bx[1], b2 = bx[2], b3 = bx[3], b4 = bx[4], b5 = bx[5];
#pragma unroll
    for (int k = 0; k < 4; ++k) {
      int px = tid + k * 1024;
      int h = px >> 6, w = px & 63;
      float xs = (2.0f * w + 1.0f) / 64.0f - 1.0f;
      float ys = (2.0f * h + 1.0f) / 64.0f - 1.0f;
      float gx = g0 * xs + g1 * ys + g2;
      float gy = g3 * xs + g4 * ys + g5;
      float ix = ((gx + 1.0f) * 64.0f - 1.0f) * 0.5f;
      float iy = ((gy + 1.0f) * 64.0f - 1.0f) * 0.5f;
      float x0 = floorf(ix), y0 = floorf(iy);
      float wx = ix - x0, wy = iy - y0;
      float v[2][2];
#pragma unroll
      for (int dy = 0; dy < 2; ++dy)
#pragma unroll
        for (int dx = 0; dx < 2; ++dx) {
          float xf = x0 + dx, yf = y0 + dy;
          bool valid = (xf >= 0.0f) && (xf <= 63.0f) && (yf >= 0.0f) && (yf <= 63.0f);
          int xi = (int)fminf(fmaxf(xf, 0.0f), 63.0f);
          int yi = (int)fminf(fmaxf(yf, 0.0f), 63.0f);
          v[dy][dx] = valid ? pl[yi * 64 + xi] : 0.0f;
        }
      float samp = (1.0f - wy) * ((1.0f - wx) * v[0][0] + wx * v[0][1]) +
                   wy * ((1.0f - wx) * v[1][0] + wx * v[1][1]);
      float bgx = b0 * xs + b1 * ys + b2;
      float bgy = b3 * xs + b4 * ys + b5;
      float bix = ((bgx + 1.0f) * 64.0f - 1.0f) * 0.5f;
      float biy = ((bgy + 1.0f) * 64.0f - 1.0f) * 0.5f;
      float bx0 = floorf(bix), by0 = floorf(biy);
      float bwx = bix - bx0, bwy = biy - by0;
      float m[2][2];
#pragma unroll
      for (int dy = 0; dy < 2; ++dy)
#pragma unroll
        for (int dx = 0; dx < 2; ++dx) {
          float xf = bx0 + dx, yf = by0 + dy;
          m[dy][dx] = ((xf >= 0.0f) && (xf <= 63.0f) && (yf >= 0.0f) && (yf <= 63.0f)) ? 1.0f : 0.0f;
        }
      float mask = (1.0f - bwy) * ((1.0f - bwx) * m[0][0] + bwx * m[0][1]) +
                   bwy * ((1.0f - bwx) * m[1][0] + bwx * m[1][1]);
      sp[h * 68 + w] = samp * mask;
    }
  }
  __syncthreads();

  if (tid < 256) {
    int strip = tid >> 4, w4 = (tid & 15) * 4;
    int h0 = strip * 4;
    float4 a0 = make_float4(0.f, 0.f, 0.f, 0.f), a1 = a0, a2 = a0, a3 = a0;
#pragma unroll
    for (int j = 0; j < 35; ++j) {
      int r = h0 + j - 16;
      bool valid = (r >= 0) && (r < 64);
      int rc = valid ? r : 0;
      float4 f = *reinterpret_cast<const float4*>(&sp[rc * 68 + w4]);
      f.x = valid ? f.x : 0.0f; f.y = valid ? f.y : 0.0f;
      f.z = valid ? f.z : 0.0f; f.w = valid ? f.w : 0.0f;
      if (j <= 31) { a0.x += f.x; a0.y += f.y; a0.z += f.z; a0.w += f.w; }
      if (j >= 1 && j <= 32) { a1.x += f.x; a1.y += f.y; a1.z += f.z; a1.w += f.w; }
      if (j >= 2 && j <= 33) { a2.x += f.x; a2.y += f.y; a2.z += f.z; a2.w += f.w; }
      if (j >= 3) { a3.x += f.x; a3.y += f.y; a3.z += f.z; a3.w += f.w; }
    }
    *reinterpret_cast<float4*>(&cb[(h0 + 0) * 100 + 16 + w4]) = a0;
    *reinterpret_cast<float4*>(&cb[(h0 + 1) * 100 + 16 + w4]) = a1;
    *reinterpret_cast<float4*>(&cb[(h0 + 2) * 100 + 16 + w4]) = a2;
    *reinterpret_cast<float4*>(&cb[(h0 + 3) * 100 + 16 + w4]) = a3;
  } else if (tid < 768) {
    int l = tid - 256;
    int row = l >> 3, gq = l & 7;
    int base = row * 100 + ((gq < 4) ? gq * 4 : 80 + (gq - 4) * 4);
    *reinterpret_cast<float4*>(&cb[base]) = make_float4(0.f, 0.f, 0.f, 0.f);
  }
  __syncthreads();

  float best = -3.402823466e+38f;
  int bidx = 0x7fffffff;
  {
    int h = tid >> 4, w4 = (tid & 15) * 4;
    float s0 = 0.f, s1 = 0.f, s2 = 0.f, s3 = 0.f;
#pragma unroll
    for (int q = 0; q < 9; ++q) {
      float4 f = *reinterpret_cast<const float4*>(&cb[h * 100 + w4 + 4 * q]);
      float fe[4] = {f.x, f.y, f.z, f.w};
#pragma unroll
      for (int e = 0; e < 4; ++e) {
        int u = 4 * q + e;
        if (u <= 31) s0 += fe[e];
        if (u >= 1 && u <= 32) s1 += fe[e];
        if (u >= 2 && u <= 33) s2 += fe[e];
        if (u >= 3 && u <= 34) s3 += fe[e];
      }
    }
    float sv[4] = {s0, s1, s2, s3};
#pragma unroll
    for (int d = 0; d < 4; ++d) {
      int i = (h << 6) + w4 + d;
      if (sv[d] > best) { best = sv[d]; bidx = i; }
    }
  }
#pragma unroll
  for (int off = 32; off > 0; off >>= 1) {
    float v2 = __shfl_down(best, off);
    int i2 = __shfl_down(bidx, off);
    if (v2 > best || (v2 == best && i2 < bidx)) { best = v2; bidx = i2; }
  }
  if ((tid & 63) == 0) { wv[tid >> 6] = best; wi[tid >> 6] = bidx; }
  __syncthreads();
  if (tid == 0) {
    float bv = wv[0]; int bi = wi[0];
#pragma unroll
    for (int k = 1; k < 16; ++k)
      if (wv[k] > bv || (wv[k] == bv && wi[k] < bi)) { bv = wv[k]; bi = wi[k]; }
    am_s = bi;
  }
  __syncthreads();

  int am = am_s;
  int r = am >> 6, cx = am & 63;
  float* o = out + (size_t)bc * 1024;
  {
    int oi = tid >> 5, oj = tid & 31;
    int rr = r + oi - 16, cj = cx + oj - 16;
    bool v = (rr >= 0) && (rr < 64) && (cj >= 0) && (cj < 64);
    int rrc = v ? rr : 0, cjc = v ? cj : 0;
    o[tid] = v ? sp[rrc * 68 + cjc] : 0.0f;
  }
}

// ---------------- fused 32x32 layer: GEMM (2 ch/block, grid 512) + sample + pool ----
template <bool POOL>
__global__ __launch_bounds__(256) void fused32_kernel(
    const float* __restrict__ lin, const float* __restrict__ x,
    const float* __restrict__ geo, const float* __restrict__ box,
    float* __restrict__ out, float* __restrict__ pooled) {
  const int H = 32, W = 32, HW = 1024;
  __shared__ __align__(16) float pls[2][1024];
  __shared__ float wred[8];
  int b = blockIdx.x & 7;                 // XCD swizzle: batch per XCD
  int c0 = (blockIdx.x >> 3) * 2;
  int tid = threadIdx.x;
  const float* xb = x + (size_t)b * 128 * HW;
  const float* l0 = lin + (c0 + 0) * 128;
  const float* l1 = lin + (c0 + 1) * 128;
  int px4 = tid * 4;

  float4 acc0 = make_float4(0.f, 0.f, 0.f, 0.f);
  float4 acc1 = acc0;
#pragma unroll 8
  for (int k = 0; k < 128; ++k) {
    float4 xv = *reinterpret_cast<const float4*>(&xb[(size_t)k * HW + px4]);
    float s0 = l0[k], s1 = l1[k];
    acc0.x += s0 * xv.x; acc0.y += s0 * xv.y; acc0.z += s0 * xv.z; acc0.w += s0 * xv.w;
    acc1.x += s1 * xv.x; acc1.y += s1 * xv.y; acc1.z += s1 * xv.z; acc1.w += s1 * xv.w;
  }
  *reinterpret_cast<float4*>(&pls[0][px4]) = acc0;
  *reinterpret_cast<float4*>(&pls[1][px4]) = acc1;
  __syncthreads();

  float psum[2] = {0.f, 0.f};
#pragma unroll
  for (int c = 0; c < 2; ++c) {
    const float* g = geo + (c0 + c) * 6;
    const float* bxp = box + (c0 + c) * 6;
    float g0 = g[0], g1 = g[1], g2 = g[2], g3 = g[3], g4 = g[4], g5 = g[5];
    float b0 = bxp[0], b1 = bxp[1], b2 = bxp[2], b3 = bxp[3], b4 = bxp[4], b5 = bxp[5];
    float* o = out + ((size_t)b * CC + c0 + c) * HW;
    const float* pl = pls[c];
#pragma unroll
    for (int k = 0; k < 4; ++k) {
      int px = tid + k * 256;
      int h = px >> 5, w = px & 31;
      float xs = (2.0f * w + 1.0f) / W - 1.0f;
      float ys = (2.0f * h + 1.0f) / H - 1.0f;
      float gx = g0 * xs + g1 * ys + g2;
      float gy = g3 * xs + g4 * ys + g5;
      float ix = ((gx + 1.0f) * W - 1.0f) * 0.5f;
      float iy = ((gy + 1.0f) * H - 1.0f) * 0.5f;
      float x0 = floorf(ix), y0 = floorf(iy);
      float wx = ix - x0, wy = iy - y0;
      float v[2][2];
#pragma unroll
      for (int dy = 0; dy < 2; ++dy)
#pragma unroll
        for (int dx = 0; dx < 2; ++dx) {
          float xf = x0 + dx, yf = y0 + dy;
          bool valid = (xf >= 0.0f) && (xf <= 31.0f) && (yf >= 0.0f) && (yf <= 31.0f);
          int xi = (int)fminf(fmaxf(xf, 0.0f), 31.0f);
          int yi = (int)fminf(fmaxf(yf, 0.0f), 31.0f);
          v[dy][dx] = valid ? pl[yi * 32 + xi] : 0.0f;
        }
      float samp = (1.0f - wy) * ((1.0f - wx) * v[0][0] + wx * v[0][1]) +
                   wy * ((1.0f - wx) * v[1][0] + wx * v[1][1]);
      float bgx = b0 * xs + b1 * ys + b2;
      float bgy = b3 * xs + b4 * ys + b5;
      float bix = ((bgx + 1.0f) * W - 1.0f) * 0.5f;
      float biy = ((bgy + 1.0f) * H - 1.0f) * 0.5f;
      float bx0 = floorf(bix), by0 = floorf(biy);
      float bwx = bix - bx0, bwy = biy - by0;
      float m[2][2];
#pragma unroll
      for (int dy = 0; dy < 2; ++dy)
#pragma unroll
        for (int dx = 0; dx < 2; ++dx) {
          float xf = bx0 + dx, yf = by0 + dy;
          m[dy][dx] = ((xf >= 0.0f) && (xf <= 31.0f) && (yf >= 0.0f) && (yf <= 31.0f)) ? 1.0f : 0.0f;
        }
      float mask = (1.0f - bwy) * ((1.0f - bwx) * m[0][0] + bwx * m[0][1]) +
                   bwy * ((1.0f - bwx) * m[1][0] + bwx * m[1][1]);
      float res = samp * mask;
      o[px] = res;
      if (POOL) psum[c] += res;
    }
  }
  if (POOL) {
    int lane = tid & 63, wid = tid >> 6;
#pragma unroll
    for (int c = 0; c < 2; ++c) {
      float r = psum[c];
#pragma unroll
      for (int off = 32; off > 0; off >>= 1) r += __shfl_down(r, off);
      if (lane == 0) wred[c * 4 + wid] = r;
    }
    __syncthreads();
    if (tid < 2) {
      float t = wred[tid * 4] + wred[tid * 4 + 1] + wred[tid * 4 + 2] + wred[tid * 4 + 3];
      pooled[b * CC + c0 + tid] = t * (1.0f / 1024.0f);
    }
  }
}

// ---------------- dense head ----------------
__global__ __launch_bounds__(128) void dense_kernel(
    const float* __restrict__ pooled, const float* __restrict__ w,
    const float* __restrict__ bias, float* __restrict__ out) {
  int t = threadIdx.x;
  if (t < 80) {
    int b = t / 10, o = t % 10;
    float s = bias[o];
    const float* pb = pooled + b * 128;
    const float* wo = w + o * 128;
    for (int c = 0; c < 128; ++c) s += pb[c] * wo[c];
    out[b * 10 + o] = s;
  }
}

extern "C" void kernel_launch(void* const* d_in, const int* in_sizes, int n_in,
                              void* d_out, int out_size, void* d_ws, size_t ws_size,
                              hipStream_t stream) {
  const float* x     = (const float*)d_in[0];   // [8,3,64,64]
  const float* geo0  = (const float*)d_in[1];   // [128,2,3]
  const float* lin0  = (const float*)d_in[2];   // [128,3]
  const float* box0  = (const float*)d_in[3];   // [128,2,3]
  const float* geos  = (const float*)d_in[4];   // [3,128,2,3]
  const float* lins  = (const float*)d_in[5];   // [3,128,128]
  const float* boxes = (const float*)d_in[6];   // [3,128,2,3]
  const float* dw    = (const float*)d_in[7];   // [10,128]
  const float* db    = (const float*)d_in[8];   // [10]

  float* out  = (float*)d_out;      // [8,10] then feat [8,128,32,32]
  float* feat = out + 80;
  float* ws   = (float*)d_ws;
  float* ws0  = ws;                 // 16 MB
  float* ws1  = ws + 4194304;       // 16 MB
  float* pooled = ws + 8388608;     // 1024 floats

  // inLay + layer-0 combine fused: sample B on the fly -> ws0
  inlay_gemm_kernel<<<dim3(64, BB), 256, 0, stream>>>(x, lin0, geo0, box0, lins, ws0);
  // layer 0 sample + layer 1 maxpool -> [8,128,32,32] in ws1
  sampmax_kernel<<<dim3(BB * CC), 1024, 0, stream>>>(ws0, geos, boxes, ws1);
  // layer 2: fused GEMM + sample (2 ch/block, grid 512)
  fused32_kernel<false><<<dim3(512), 256, 0, stream>>>(lins + 16384, ws1, geos + 768, boxes + 768, ws0, nullptr);
  // layer 3: fused GEMM + sample + mean-pool, feat straight to d_out
  fused32_kernel<true><<<dim3(512), 256, 0, stream>>>(lins + 32768, ws0, geos + 1536, boxes + 1536, feat, pooled);
  // head
  dense_kernel<<<1, 128, 0, stream>>>(pooled, dw, db, out);
}

// Round 11
// 170.913 us; speedup vs baseline: 1.2027x; 1.0789x over previous
//
#include <hip/hip_runtime.h>

#define BB 8
#define CC 128

// ---------------- fused inLay: global->combine->LDS(stride 68) + sample + box mask ----
__global__ __launch_bounds__(256) void inlay_sample_kernel(
    const float* __restrict__ x, const float* __restrict__ lin,
    const float* __restrict__ geo, const float* __restrict__ box,
    float* __restrict__ out) {
  const int H = 64, W = 64, HW = 4096;
  __shared__ __align__(16) float cp[64 * 68];   // 17.4 KB combined plane
  int bc = blockIdx.x;
  int c = bc & (CC - 1);
  int b = bc >> 7;
  int tid = threadIdx.x;
  const float* xb = x + (size_t)b * 3 * HW;

  float w0 = lin[c * 3 + 0], w1 = lin[c * 3 + 1], w2 = lin[c * 3 + 2];

#pragma unroll
  for (int k = 0; k < 4; ++k) {
    int i4 = tid + k * 256;
    int base = i4 * 4;
    float4 f0 = *reinterpret_cast<const float4*>(&xb[base]);
    float4 f1 = *reinterpret_cast<const float4*>(&xb[HW + base]);
    float4 f2 = *reinterpret_cast<const float4*>(&xb[2 * HW + base]);
    float4 cv;
    cv.x = w0 * f0.x + w1 * f1.x + w2 * f2.x;
    cv.y = w0 * f0.y + w1 * f1.y + w2 * f2.y;
    cv.z = w0 * f0.z + w1 * f1.z + w2 * f2.z;
    cv.w = w0 * f0.w + w1 * f1.w + w2 * f2.w;
    int h = i4 >> 4, w = (i4 & 15) * 4;
    *reinterpret_cast<float4*>(&cp[h * 68 + w]) = cv;
  }
  __syncthreads();

  const float* g = geo + c * 6;
  const float* bx = box + c * 6;
  float g0 = g[0], g1 = g[1], g2 = g[2], g3 = g[3], g4 = g[4], g5 = g[5];
  float b0 = bx[0], b1 = bx[1], b2 = bx[2], b3 = bx[3], b4 = bx[4], b5 = bx[5];
  float* o = out + ((size_t)b * CC + c) * HW;

#pragma unroll
  for (int k = 0; k < 16; ++k) {
    int px = tid + k * 256;
    int h = px >> 6, w = px & 63;
    float xs = (2.0f * w + 1.0f) / W - 1.0f;
    float ys = (2.0f * h + 1.0f) / H - 1.0f;
    float gx = g0 * xs + g1 * ys + g2;
    float gy = g3 * xs + g4 * ys + g5;
    float ix = ((gx + 1.0f) * W - 1.0f) * 0.5f;
    float iy = ((gy + 1.0f) * H - 1.0f) * 0.5f;
    float x0 = floorf(ix), y0 = floorf(iy);
    float wx = ix - x0, wy = iy - y0;
    float v[2][2];
#pragma unroll
    for (int dy = 0; dy < 2; ++dy)
#pragma unroll
      for (int dx = 0; dx < 2; ++dx) {
        float xf = x0 + dx, yf = y0 + dy;
        bool valid = (xf >= 0.0f) && (xf <= 63.0f) && (yf >= 0.0f) && (yf <= 63.0f);
        int xi = (int)fminf(fmaxf(xf, 0.0f), 63.0f);
        int yi = (int)fminf(fmaxf(yf, 0.0f), 63.0f);
        v[dy][dx] = valid ? cp[yi * 68 + xi] : 0.0f;
      }
    float samp = (1.0f - wy) * ((1.0f - wx) * v[0][0] + wx * v[0][1]) +
                 wy * ((1.0f - wx) * v[1][0] + wx * v[1][1]);

    float bgx = b0 * xs + b1 * ys + b2;
    float bgy = b3 * xs + b4 * ys + b5;
    float bix = ((bgx + 1.0f) * W - 1.0f) * 0.5f;
    float biy = ((bgy + 1.0f) * H - 1.0f) * 0.5f;
    float bx0 = floorf(bix), by0 = floorf(biy);
    float bwx = bix - bx0, bwy = biy - by0;
    float m[2][2];
#pragma unroll
    for (int dy = 0; dy < 2; ++dy)
#pragma unroll
      for (int dx = 0; dx < 2; ++dx) {
        float xf = bx0 + dx, yf = by0 + dy;
        m[dy][dx] = ((xf >= 0.0f) && (xf <= 63.0f) && (yf >= 0.0f) && (yf <= 63.0f)) ? 1.0f : 0.0f;
      }
    float mask = (1.0f - bwy) * ((1.0f - bwx) * m[0][0] + bwx * m[0][1]) +
                 bwy * ((1.0f - bwx) * m[1][0] + bwx * m[1][1]);
    o[px] = samp * mask;
  }
}

// ---------------- layer-0 GEMM: 64x64 tile, 4x4/thread, register prefetch ----------
__global__ __launch_bounds__(256) void gemm64_kernel(
    const float* __restrict__ lin, const float* __restrict__ x,
    float* __restrict__ y, int HW) {
  const int Ci = 128;
  __shared__ __align__(16) float As[16][68];
  __shared__ __align__(16) float Bs[16][64];
  int b = blockIdx.z;
  const float* xb = x + (size_t)b * Ci * HW;
  float* yb = y + (size_t)b * CC * HW;
  int tid = threadIdx.x;
  int tx = tid & 15, ty = tid >> 4;
  int row0 = blockIdx.y * 64;
  int col0 = blockIdx.x * 64;
  int m = tid >> 2, kq = (tid & 3) * 4;
  int kk = tid >> 4, n4 = (tid & 15) * 4;
  float acc[4][4] = {};
  float4 ra = *reinterpret_cast<const float4*>(&lin[(row0 + m) * Ci + kq]);
  float4 rb = *reinterpret_cast<const float4*>(&xb[(size_t)kk * HW + col0 + n4]);
  for (int k0 = 0; k0 < 128; k0 += 16) {
    __syncthreads();
    As[kq + 0][m] = ra.x; As[kq + 1][m] = ra.y; As[kq + 2][m] = ra.z; As[kq + 3][m] = ra.w;
    *reinterpret_cast<float4*>(&Bs[kk][n4]) = rb;
    __syncthreads();
    if (k0 + 16 < 128) {
      ra = *reinterpret_cast<const float4*>(&lin[(row0 + m) * Ci + k0 + 16 + kq]);
      rb = *reinterpret_cast<const float4*>(&xb[(size_t)(k0 + 16 + kk) * HW + col0 + n4]);
    }
#pragma unroll
    for (int kki = 0; kki < 16; ++kki) {
      float4 a4 = *reinterpret_cast<const float4*>(&As[kki][ty * 4]);
      float4 b4 = *reinterpret_cast<const float4*>(&Bs[kki][tx * 4]);
      float a[4] = {a4.x, a4.y, a4.z, a4.w};
      float bv[4] = {b4.x, b4.y, b4.z, b4.w};
#pragma unroll
      for (int i = 0; i < 4; i++)
#pragma unroll
        for (int j = 0; j < 4; j++) acc[i][j] += a[i] * bv[j];
    }
  }
#pragma unroll
  for (int i = 0; i < 4; i++) {
    float* yr = yb + (size_t)(row0 + ty * 4 + i) * HW + col0 + tx * 4;
    *reinterpret_cast<float4*>(yr) = make_float4(acc[i][0], acc[i][1], acc[i][2], acc[i][3]);
  }
}

// ---------------- fused sample(64x64) + MaxPool2d_G -> 32x32, 1024 threads ---------
// cb phase: one output row per thread (all 1024 busy); per-row term order identical
// to the 4-row-strip version (r ascending, exact-0 masked) -> bit-identical argmax.
__global__ __launch_bounds__(1024, 4) void sampmax_kernel(
    const float* __restrict__ y, const float* __restrict__ geo,
    const float* __restrict__ box, float* __restrict__ out) {
  __shared__ __align__(16) float sp[64 * 68];
  __shared__ __align__(16) float arena[64 * 100];
  __shared__ float wv[16];
  __shared__ int wi[16];
  __shared__ int am_s;
  float* pl = arena;
  float* cb = arena;

  int bc = blockIdx.x;
  int c = bc & (CC - 1);
  int b = bc >> 7;
  int tid = threadIdx.x;

  const float* plane = y + (size_t)bc * 4096;
  *reinterpret_cast<float4*>(&pl[tid * 4]) = *reinterpret_cast<const float4*>(&plane[tid * 4]);
  __syncthreads();

  {
    const float* g = geo + c * 6;
    const float* bx = box + c * 6;
    float g0 = g[0], g1 = g[1], g2 = g[2], g3 = g[3], g4 = g[4], g5 = g[5];
    float b0 = bx[0], b1 = bx[1], b2 = bx[2], b3 = bx[3], b4 = bx[4], b5 = bx[5];
#pragma unroll
    for (int k = 0; k < 4; ++k) {
      int px = tid + k * 1024;
      int h = px >> 6, w = px & 63;
      float xs = (2.0f * w + 1.0f) / 64.0f - 1.0f;
      float ys = (2.0f * h + 1.0f) / 64.0f - 1.0f;
      float gx = g0 * xs + g1 * ys + g2;
      float gy = g3 * xs + g4 * ys + g5;
      float ix = ((gx + 1.0f) * 64.0f - 1.0f) * 0.5f;
      float iy = ((gy + 1.0f) * 64.0f - 1.0f) * 0.5f;
      float x0 = floorf(ix), y0 = floorf(iy);
      float wx = ix - x0, wy = iy - y0;
      float v[2][2];
#pragma unroll
      for (int dy = 0; dy < 2; ++dy)
#pragma unroll
        for (int dx = 0; dx < 2; ++dx) {
          float xf = x0 + dx, yf = y0 + dy;
          bool valid = (xf >= 0.0f) && (xf <= 63.0f) && (yf >= 0.0f) && (yf <= 63.0f);
          int xi = (int)fminf(fmaxf(xf, 0.0f), 63.0f);
          int yi = (int)fminf(fmaxf(yf, 0.0f), 63.0f);
          v[dy][dx] = valid ? pl[yi * 64 + xi] : 0.0f;
        }
      float samp = (1.0f - wy) * ((1.0f - wx) * v[0][0] + wx * v[0][1]) +
                   wy * ((1.0f - wx) * v[1][0] + wx * v[1][1]);
      float bgx = b0 * xs + b1 * ys + b2;
      float bgy = b3 * xs + b4 * ys + b5;
      float bix = ((bgx + 1.0f) * 64.0f - 1.0f) * 0.5f;
      float biy = ((bgy + 1.0f) * 64.0f - 1.0f) * 0.5f;
      float bx0 = floorf(bix), by0 = floorf(biy);
      float bwx = bix - bx0, bwy = biy - by0;
      float m[2][2];
#pragma unroll
      for (int dy = 0; dy < 2; ++dy)
#pragma unroll
        for (int dx = 0; dx < 2; ++dx) {
          float xf = bx0 + dx, yf = by0 + dy;
          m[dy][dx] = ((xf >= 0.0f) && (xf <= 63.0f) && (yf >= 0.0f) && (yf <= 63.0f)) ? 1.0f : 0.0f;
        }
      float mask = (1.0f - bwy) * ((1.0f - bwx) * m[0][0] + bwx * m[0][1]) +
                   bwy * ((1.0f - bwx) * m[1][0] + bwx * m[1][1]);
      sp[h * 68 + w] = samp * mask;
    }
  }
  __syncthreads();

  // phase 3: column band sums — one (h, w4) output group per thread (1024 total)
  {
    int h = tid >> 4, w4 = (tid & 15) * 4;
    float4 a = make_float4(0.f, 0.f, 0.f, 0.f);
#pragma unroll
    for (int j = 0; j < 32; ++j) {
      int r = h + j - 16;
      bool valid = (r >= 0) && (r < 64);
      int rc = valid ? r : 0;
      float4 f = *reinterpret_cast<const float4*>(&sp[rc * 68 + w4]);
      f.x = valid ? f.x : 0.0f; f.y = valid ? f.y : 0.0f;
      f.z = valid ? f.z : 0.0f; f.w = valid ? f.w : 0.0f;
      a.x += f.x; a.y += f.y; a.z += f.z; a.w += f.w;
    }
    *reinterpret_cast<float4*>(&cb[h * 100 + 16 + w4]) = a;
    if (tid < 512) {   // zero side pads: 64 rows x 8 float4s
      int row = tid >> 3, gq = tid & 7;
      int base = row * 100 + ((gq < 4) ? gq * 4 : 80 + (gq - 4) * 4);
      *reinterpret_cast<float4*>(&cb[base]) = make_float4(0.f, 0.f, 0.f, 0.f);
    }
  }
  __syncthreads();

  float best = -3.402823466e+38f;
  int bidx = 0x7fffffff;
  {
    int h = tid >> 4, w4 = (tid & 15) * 4;
    float s0 = 0.f, s1 = 0.f, s2 = 0.f, s3 = 0.f;
#pragma unroll
    for (int q = 0; q < 9; ++q) {
      float4 f = *reinterpret_cast<const float4*>(&cb[h * 100 + w4 + 4 * q]);
      float fe[4] = {f.x, f.y, f.z, f.w};
#pragma unroll
      for (int e = 0; e < 4; ++e) {
        int u = 4 * q + e;
        if (u <= 31) s0 += fe[e];
        if (u >= 1 && u <= 32) s1 += fe[e];
        if (u >= 2 && u <= 33) s2 += fe[e];
        if (u >= 3 && u <= 34) s3 += fe[e];
      }
    }
    float sv[4] = {s0, s1, s2, s3};
#pragma unroll
    for (int d = 0; d < 4; ++d) {
      int i = (h << 6) + w4 + d;
      if (sv[d] > best) { best = sv[d]; bidx = i; }
    }
  }
#pragma unroll
  for (int off = 32; off > 0; off >>= 1) {
    float v2 = __shfl_down(best, off);
    int i2 = __shfl_down(bidx, off);
    if (v2 > best || (v2 == best && i2 < bidx)) { best = v2; bidx = i2; }
  }
  if ((tid & 63) == 0) { wv[tid >> 6] = best; wi[tid >> 6] = bidx; }
  __syncthreads();
  if (tid == 0) {
    float bv = wv[0]; int bi = wi[0];
#pragma unroll
    for (int k = 1; k < 16; ++k)
      if (wv[k] > bv || (wv[k] == bv && wi[k] < bi)) { bv = wv[k]; bi = wi[k]; }
    am_s = bi;
  }
  __syncthreads();

  int am = am_s;
  int r = am >> 6, cx = am & 63;
  float* o = out + (size_t)bc * 1024;
  {
    int oi = tid >> 5, oj = tid & 31;
    int rr = r + oi - 16, cj = cx + oj - 16;
    bool v = (rr >= 0) && (rr < 64) && (cj >= 0) && (cj < 64);
    int rrc = v ? rr : 0, cjc = v ? cj : 0;
    o[tid] = v ? sp[rrc * 68 + cjc] : 0.0f;
  }
}

// ---------------- fused 32x32 layer: 512 threads, 2 ch/block, k-split 2-way --------
// k-split reorders the fp32 sum — safe: layers 2/3 are post-argmax, threshold loose.
template <bool POOL>
__global__ __launch_bounds__(512) void fused32_kernel(
    const float* __restrict__ lin, const float* __restrict__ x,
    const float* __restrict__ geo, const float* __restrict__ box,
    float* __restrict__ out, float* __restrict__ pooled) {
  const int H = 32, W = 32, HW = 1024;
  __shared__ __align__(16) float pls[2][1024];
  __shared__ __align__(16) float part[2][1024];
  __shared__ float wred[16];
  int b = blockIdx.x & 7;                 // XCD swizzle: batch per XCD
  int c0 = (blockIdx.x >> 3) * 2;
  int tid = threadIdx.x;
  int g4 = tid & 255;                     // float4 pixel group
  int half = tid >> 8;                    // 0/1 : k range split (wave-uniform)
  const float* xb = x + (size_t)b * 128 * HW;
  const float* l0 = lin + (c0 + 0) * 128;
  const float* l1 = lin + (c0 + 1) * 128;
  int px4 = g4 * 4;

  float4 acc0 = make_float4(0.f, 0.f, 0.f, 0.f);
  float4 acc1 = acc0;
  int kb = half * 64;
#pragma unroll 8
  for (int kk = 0; kk < 64; ++kk) {
    int k = kb + kk;
    float4 xv = *reinterpret_cast<const float4*>(&xb[(size_t)k * HW + px4]);
    float s0 = l0[k], s1 = l1[k];
    acc0.x += s0 * xv.x; acc0.y += s0 * xv.y; acc0.z += s0 * xv.z; acc0.w += s0 * xv.w;
    acc1.x += s1 * xv.x; acc1.y += s1 * xv.y; acc1.z += s1 * xv.z; acc1.w += s1 * xv.w;
  }
  if (half == 1) {
    *reinterpret_cast<float4*>(&part[0][px4]) = acc0;
    *reinterpret_cast<float4*>(&part[1][px4]) = acc1;
  }
  __syncthreads();
  if (half == 0) {
    float4 p0 = *reinterpret_cast<const float4*>(&part[0][px4]);
    float4 p1 = *reinterpret_cast<const float4*>(&part[1][px4]);
    acc0.x += p0.x; acc0.y += p0.y; acc0.z += p0.z; acc0.w += p0.w;
    acc1.x += p1.x; acc1.y += p1.y; acc1.z += p1.z; acc1.w += p1.w;
    *reinterpret_cast<float4*>(&pls[0][px4]) = acc0;
    *reinterpret_cast<float4*>(&pls[1][px4]) = acc1;
  }
  __syncthreads();

  float psum[2] = {0.f, 0.f};
#pragma unroll
  for (int c = 0; c < 2; ++c) {
    const float* g = geo + (c0 + c) * 6;
    const float* bxp = box + (c0 + c) * 6;
    float g0 = g[0], g1 = g[1], g2 = g[2], g3 = g[3], g4 = g[4], g5 = g[5];
    float b0 = bxp[0], b1 = bxp[1], b2 = bxp[2], b3 = bxp[3], b4 = bxp[4], b5 = bxp[5];
    float* o = out + ((size_t)b * CC + c0 + c) * HW;
    const float* pl = pls[c];
#pragma unroll
    for (int k = 0; k < 2; ++k) {
      int px = tid + k * 512;
      int h = px >> 5, w = px & 31;
      float xs = (2.0f * w + 1.0f) / W - 1.0f;
      float ys = (2.0f * h + 1.0f) / H - 1.0f;
      float gx = g0 * xs + g1 * ys + g2;
      float gy = g3 * xs + g4 * ys + g5;
      float ix = ((gx + 1.0f) * W - 1.0f) * 0.5f;
      float iy = ((gy + 1.0f) * H - 1.0f) * 0.5f;
      float x0 = floorf(ix), y0 = floorf(iy);
      float wx = ix - x0, wy = iy - y0;
      float v[2][2];
#pragma unroll
      for (int dy = 0; dy < 2; ++dy)
#pragma unroll
        for (int dx = 0; dx < 2; ++dx) {
          float xf = x0 + dx, yf = y0 + dy;
          bool valid = (xf >= 0.0f) && (xf <= 31.0f) && (yf >= 0.0f) && (yf <= 31.0f);
          int xi = (int)fminf(fmaxf(xf, 0.0f), 31.0f);
          int yi = (int)fminf(fmaxf(yf, 0.0f), 31.0f);
          v[dy][dx] = valid ? pl[yi * 32 + xi] : 0.0f;
        }
      float samp = (1.0f - wy) * ((1.0f - wx) * v[0][0] + wx * v[0][1]) +
                   wy * ((1.0f - wx) * v[1][0] + wx * v[1][1]);
      float bgx = b0 * xs + b1 * ys + b2;
      float bgy = b3 * xs + b4 * ys + b5;
      float bix = ((bgx + 1.0f) * W - 1.0f) * 0.5f;
      float biy = ((bgy + 1.0f) * H - 1.0f) * 0.5f;
      float bx0 = floorf(bix), by0 = floorf(biy);
      float bwx = bix - bx0, bwy = biy - by0;
      float m[2][2];
#pragma unroll
      for (int dy = 0; dy < 2; ++dy)
#pragma unroll
        for (int dx = 0; dx < 2; ++dx) {
          float xf = bx0 + dx, yf = by0 + dy;
          m[dy][dx] = ((xf >= 0.0f) && (xf <= 31.0f) && (yf >= 0.0f) && (yf <= 31.0f)) ? 1.0f : 0.0f;
        }
      float mask = (1.0f - bwy) * ((1.0f - bwx) * m[0][0] + bwx * m[0][1]) +
                   bwy * ((1.0f - bwx) * m[1][0] + bwx * m[1][1]);
      float res = samp * mask;
      o[px] = res;
      if (POOL) psum[c] += res;
    }
  }
  if (POOL) {
    int lane = tid & 63, wid = tid >> 6;   // 8 waves
#pragma unroll
    for (int c = 0; c < 2; ++c) {
      float r = psum[c];
#pragma unroll
      for (int off = 32; off > 0; off >>= 1) r += __shfl_down(r, off);
      if (lane == 0) wred[c * 8 + wid] = r;
    }
    __syncthreads();
    if (tid < 2) {
      float t = 0.0f;
#pragma unroll
      for (int wdx = 0; wdx < 8; ++wdx) t += wred[tid * 8 + wdx];
      pooled[b * CC + c0 + tid] = t * (1.0f / 1024.0f);
    }
  }
}

// ---------------- dense head ----------------
__global__ __launch_bounds__(128) void dense_kernel(
    const float* __restrict__ pooled, const float* __restrict__ w,
    const float* __restrict__ bias, float* __restrict__ out) {
  int t = threadIdx.x;
  if (t < 80) {
    int b = t / 10, o = t % 10;
    float s = bias[o];
    const float* pb = pooled + b * 128;
    const float* wo = w + o * 128;
    for (int c = 0; c < 128; ++c) s += pb[c] * wo[c];
    out[b * 10 + o] = s;
  }
}

extern "C" void kernel_launch(void* const* d_in, const int* in_sizes, int n_in,
                              void* d_out, int out_size, void* d_ws, size_t ws_size,
                              hipStream_t stream) {
  const float* x     = (const float*)d_in[0];   // [8,3,64,64]
  const float* geo0  = (const float*)d_in[1];   // [128,2,3]
  const float* lin0  = (const float*)d_in[2];   // [128,3]
  const float* box0  = (const float*)d_in[3];   // [128,2,3]
  const float* geos  = (const float*)d_in[4];   // [3,128,2,3]
  const float* lins  = (const float*)d_in[5];   // [3,128,128]
  const float* boxes = (const float*)d_in[6];   // [3,128,2,3]
  const float* dw    = (const float*)d_in[7];   // [10,128]
  const float* db    = (const float*)d_in[8];   // [10]

  float* out  = (float*)d_out;      // [8,10] then feat [8,128,32,32]
  float* feat = out + 80;
  float* ws   = (float*)d_ws;
  float* ws0  = ws;                 // 16 MB
  float* ws1  = ws + 4194304;       // 16 MB
  float* pooled = ws + 8388608;     // 1024 floats

  // inLay: fused combine(Ci=3) + sample -> ws1
  inlay_sample_kernel<<<dim3(BB * CC), 256, 0, stream>>>(x, lin0, geo0, box0, ws1);
  // layer 0: combine (64x64 tiles) -> fused sample+maxpool -> 32x32
  gemm64_kernel<<<dim3(64, 2, BB), 256, 0, stream>>>(lins, ws1, ws0, 4096);
  sampmax_kernel<<<dim3(BB * CC), 1024, 0, stream>>>(ws0, geos, boxes, ws1);
  // layer 2: fused GEMM + sample (2 ch/block, 512 threads, k-split)
  fused32_kernel<false><<<dim3(512), 512, 0, stream>>>(lins + 16384, ws1, geos + 768, boxes + 768, ws0, nullptr);
  // layer 3: fused GEMM + sample + mean-pool, feat straight to d_out
  fused32_kernel<true><<<dim3(512), 512, 0, stream>>>(lins + 32768, ws0, geos + 1536, boxes + 1536, feat, pooled);
  // head
  dense_kernel<<<1, 128, 0, stream>>>(pooled, dw, db, out);
}